// Round 1
// baseline (553.883 us; speedup 1.0000x reference)
//
#include <hip/hip_runtime.h>
#include <hip/hip_bf16.h>
#include <stdint.h>

typedef _Float16 f16;
typedef __attribute__((ext_vector_type(8))) _Float16 f16x8;
typedef __attribute__((ext_vector_type(4))) float f32x4;

__device__ __forceinline__ void g2l16(const void* g, void* l) {
  __builtin_amdgcn_global_load_lds(
      (const __attribute__((address_space(1))) uint32_t*)g,
      (__attribute__((address_space(3))) uint32_t*)l, 16, 0, 0);
}

// ---------------- weight transpose + fp32->f16 convert ----------------
// W: K x N (row-major fp32)  ->  Wt: N x K (row-major f16)
__global__ __launch_bounds__(256)
void wconv_kernel(const float* __restrict__ W, f16* __restrict__ Wt, int K, int N)
{
  __shared__ float tile[32][33];
  int n0 = blockIdx.x * 32, k0 = blockIdx.y * 32;
  int tx = threadIdx.x & 31, ty = threadIdx.x >> 5;  // ty 0..7
#pragma unroll
  for (int i = 0; i < 4; ++i)
    tile[ty + 8*i][tx] = W[(size_t)(k0 + ty + 8*i) * N + (n0 + tx)];
  __syncthreads();
#pragma unroll
  for (int i = 0; i < 4; ++i)
    Wt[(size_t)(n0 + ty + 8*i) * K + (k0 + tx)] = (f16)tile[tx][ty + 8*i];
}

// ---------------- scaled = x*lr + x0*lx ; pre = rmsnorm(scaled) ----------------
__global__ __launch_bounds__(256)
void scale_rms_kernel(const float* __restrict__ x, const float* __restrict__ x0,
                      const float* __restrict__ lamR, const float* __restrict__ lamX,
                      float* __restrict__ scaled, f16* __restrict__ pre)
{
  const int C = 1024;
  int row = blockIdx.x, tid = threadIdx.x;
  float lr = lamR[0], lx = lamX[0];
  size_t base = (size_t)row * C;
  float4 xv = ((const float4*)(x + base))[tid];
  float4 zv = ((const float4*)(x0 + base))[tid];
  float4 sv;
  sv.x = xv.x*lr + zv.x*lx;  sv.y = xv.y*lr + zv.y*lx;
  sv.z = xv.z*lr + zv.z*lx;  sv.w = xv.w*lr + zv.w*lx;
  float ss = sv.x*sv.x + sv.y*sv.y + sv.z*sv.z + sv.w*sv.w;
#pragma unroll
  for (int off = 32; off >= 1; off >>= 1) ss += __shfl_xor(ss, off);
  __shared__ float red[4];
  if ((tid & 63) == 0) red[tid >> 6] = ss;
  __syncthreads();
  float tot = red[0] + red[1] + red[2] + red[3];
  float rs = rsqrtf(tot * (1.0f / 1024.0f) + 1e-5f);
  ((float4*)(scaled + base))[tid] = sv;
  f16* p = pre + base + tid * 4;
  p[0] = (f16)(sv.x * rs); p[1] = (f16)(sv.y * rs);
  p[2] = (f16)(sv.z * rs); p[3] = (f16)(sv.w * rs);
}

// ---------------- pre2 = rmsnorm(fp32 in) as f16 ----------------
__global__ __launch_bounds__(256)
void rms_kernel(const float* __restrict__ xin, f16* __restrict__ outp)
{
  const int C = 1024;
  int row = blockIdx.x, tid = threadIdx.x;
  size_t base = (size_t)row * C;
  float4 sv = ((const float4*)(xin + base))[tid];
  float ss = sv.x*sv.x + sv.y*sv.y + sv.z*sv.z + sv.w*sv.w;
#pragma unroll
  for (int off = 32; off >= 1; off >>= 1) ss += __shfl_xor(ss, off);
  __shared__ float red[4];
  if ((tid & 63) == 0) red[tid >> 6] = ss;
  __syncthreads();
  float tot = red[0] + red[1] + red[2] + red[3];
  float rs = rsqrtf(tot * (1.0f / 1024.0f) + 1e-5f);
  f16* p = outp + base + tid * 4;
  p[0] = (f16)(sv.x * rs); p[1] = (f16)(sv.y * rs);
  p[2] = (f16)(sv.z * rs); p[3] = (f16)(sv.w * rs);
}

// ---------------- in-place RoPE + rmsnorm on (B*T, H, 64) f16 ----------------
__global__ __launch_bounds__(256)
void rope_rms_kernel(f16* __restrict__ X, const float* __restrict__ cs,
                     const float* __restrict__ sn)
{
  int ridx = blockIdx.x * 4 + (threadIdx.x >> 6);  // over B*T*H
  int lane = threadIdx.x & 63;
  int h = ridx & 15;         // H = 16
  int bt = ridx >> 4;
  int t = bt & 2047;         // T = 2048
  size_t base = (size_t)bt * 1024 + h * 64;
  float xv = (float)X[base + lane];
  float other = __shfl_xor(xv, 32);
  float rot = (lane < 32) ? -other : other;   // concat([-x2, x1])
  float c = cs[t * 64 + lane], s = sn[t * 64 + lane];
  float y = xv * c + rot * s;
  float ss = y * y;
#pragma unroll
  for (int off = 32; off >= 1; off >>= 1) ss += __shfl_xor(ss, off);
  float r = rsqrtf(ss * (1.0f / 64.0f) + 1e-5f);
  X[base + lane] = (f16)(y * r);
}

// ---------------- GEMM: C[M,N] = A[M,K] @ Bt[N,K]^T, f16 in, fp32 acc ----------------
// EPI 0: f16 out ; EPI 1: f16 relu(v)^2 ; EPI 2: fp32 out = resid + v
template<int EPI>
__global__ __launch_bounds__(256)
void gemm_kernel(const f16* __restrict__ A, const f16* __restrict__ Bt,
                 const float* __restrict__ resid, void* __restrict__ out,
                 int M, int N, int K)
{
  __shared__ __align__(16) f16 As[128 * 32];
  __shared__ __align__(16) f16 Bs[128 * 32];
  const int tid = threadIdx.x;
  const int wave = tid >> 6, lane = tid & 63;
  const int col = lane & 15, quad = lane >> 4;
  const int m0 = blockIdx.y * 128, n0 = blockIdx.x * 128;
  const int wm = (wave >> 1) * 64, wn = (wave & 1) * 64;
  f32x4 acc[4][4] = {};

  const size_t rowb = (size_t)K * 2;
  const char* Agp = (const char*)A  + (size_t)m0 * rowb;
  const char* Bgp = (const char*)Bt + (size_t)n0 * rowb;

  for (int k0 = 0; k0 < K; k0 += 32) {
#pragma unroll
    for (int i = 0; i < 2; ++i) {
      int e = i * 256 + tid;
      int r = e >> 2;
      int cb = (e & 3) << 4;
      int lbase = (i * 256 + wave * 64) << 4;   // wave-uniform; HW adds lane*16
      g2l16(Agp + (size_t)r * rowb + (size_t)k0 * 2 + cb, (char*)As + lbase);
      g2l16(Bgp + (size_t)r * rowb + (size_t)k0 * 2 + cb, (char*)Bs + lbase);
    }
    __syncthreads();
    f16x8 af[4], bf[4];
#pragma unroll
    for (int t = 0; t < 4; ++t)
      af[t] = *(const f16x8*)(As + (wm + t*16 + col) * 32 + quad * 8);
#pragma unroll
    for (int t = 0; t < 4; ++t)
      bf[t] = *(const f16x8*)(Bs + (wn + t*16 + col) * 32 + quad * 8);
#pragma unroll
    for (int mt = 0; mt < 4; ++mt)
#pragma unroll
      for (int nt = 0; nt < 4; ++nt)
        acc[mt][nt] = __builtin_amdgcn_mfma_f32_16x16x32_f16(af[mt], bf[nt], acc[mt][nt], 0, 0, 0);
    __syncthreads();
  }
#pragma unroll
  for (int mt = 0; mt < 4; ++mt) {
#pragma unroll
    for (int nt = 0; nt < 4; ++nt) {
#pragma unroll
      for (int r = 0; r < 4; ++r) {
        int row = m0 + wm + mt * 16 + quad * 4 + r;   // C/D: row = quad*4+reg
        int cc  = n0 + wn + nt * 16 + col;            //      col = lane&15
        size_t idx = (size_t)row * N + cc;
        float v = acc[mt][nt][r];
        if (EPI == 0) {
          ((f16*)out)[idx] = (f16)v;
        } else if (EPI == 1) {
          float tv = v > 0.0f ? v : 0.0f;
          ((f16*)out)[idx] = (f16)(tv * tv);
        } else {
          ((float*)out)[idx] = resid[idx] + v;
        }
      }
    }
  }
}

// ---------------- causal flash attention, hd=64, f16 in/out ----------------
__global__ __launch_bounds__(256)
void attn_kernel(const f16* __restrict__ Q, const f16* __restrict__ Kc,
                 const f16* __restrict__ V, f16* __restrict__ O)
{
  const int T = 2048, C = 1024;
  __shared__ __align__(16) f16 Ks[32 * 64];
  __shared__ __align__(16) f16 Vt[64 * 32];
  __shared__ __align__(16) f16 Ps[4][16 * 32];
  const int tid = threadIdx.x, wave = tid >> 6, lane = tid & 63;
  const int col = lane & 15, quad = lane >> 4;
  const int bh = blockIdx.x;
  const int b = bh >> 4, h = bh & 15;
  const int q0 = blockIdx.y * 64;

  const f16* qb = Q  + ((size_t)b * T) * C + h * 64;
  const f16* kb = Kc + ((size_t)b * T) * C + h * 64;
  const f16* vb = V  + ((size_t)b * T) * C + h * 64;

  const int qrow_lane = q0 + wave * 16 + col;
  f16x8 aq[2];
#pragma unroll
  for (int c = 0; c < 2; ++c)
    aq[c] = *(const f16x8*)(qb + (size_t)qrow_lane * C + c * 32 + quad * 8);

  float m_i[4], l_i[4];
  f32x4 o_acc[4];
#pragma unroll
  for (int r = 0; r < 4; ++r) { m_i[r] = -1e30f; l_i[r] = 0.0f; }
#pragma unroll
  for (int d = 0; d < 4; ++d) o_acc[d] = (f32x4){0.f, 0.f, 0.f, 0.f};

  const int ntiles = (q0 + 64) >> 5;
  for (int kt = 0; kt < ntiles; ++kt) {
    const int ks0 = kt * 32;
    {  // stage K tile [32 keys][64 hd] via async 16B
      int r = tid >> 3, cb = (tid & 7) << 4;
      g2l16((const char*)kb + (size_t)(ks0 + r) * (C * 2) + cb,
            (char*)Ks + wave * 1024);
    }
    {  // stage V transposed: Vt[hd][key]
      int key = tid >> 3;
#pragma unroll
      for (int i = 0; i < 8; ++i) {
        int d = (tid & 7) + 8 * i;
        Vt[d * 32 + key] = vb[(size_t)(ks0 + key) * C + d];
      }
    }
    __syncthreads();

    f32x4 s0 = {0.f,0.f,0.f,0.f}, s1 = {0.f,0.f,0.f,0.f};
    {
      f16x8 bk;
      bk = *(const f16x8*)(Ks + (col) * 64 + quad * 8);
      s0 = __builtin_amdgcn_mfma_f32_16x16x32_f16(aq[0], bk, s0, 0, 0, 0);
      bk = *(const f16x8*)(Ks + (col) * 64 + 32 + quad * 8);
      s0 = __builtin_amdgcn_mfma_f32_16x16x32_f16(aq[1], bk, s0, 0, 0, 0);
      bk = *(const f16x8*)(Ks + (16 + col) * 64 + quad * 8);
      s1 = __builtin_amdgcn_mfma_f32_16x16x32_f16(aq[0], bk, s1, 0, 0, 0);
      bk = *(const f16x8*)(Ks + (16 + col) * 64 + 32 + quad * 8);
      s1 = __builtin_amdgcn_mfma_f32_16x16x32_f16(aq[1], bk, s1, 0, 0, 0);
    }
#pragma unroll
    for (int r = 0; r < 4; ++r) {
      int qr = q0 + wave * 16 + quad * 4 + r;
      float a0 = s0[r] * 0.125f, a1 = s1[r] * 0.125f;
      if (ks0 + col > qr)      a0 = -1e9f;
      if (ks0 + 16 + col > qr) a1 = -1e9f;
      float mt = fmaxf(a0, a1);
#pragma unroll
      for (int off = 8; off >= 1; off >>= 1)
        mt = fmaxf(mt, __shfl_xor(mt, off, 16));
      float mnew = fmaxf(m_i[r], mt);
      float alpha = __expf(m_i[r] - mnew);
      float p0 = __expf(a0 - mnew), p1 = __expf(a1 - mnew);
      float prt = p0 + p1;
#pragma unroll
      for (int off = 8; off >= 1; off >>= 1)
        prt += __shfl_xor(prt, off, 16);
      l_i[r] = l_i[r] * alpha + prt;
      m_i[r] = mnew;
#pragma unroll
      for (int d = 0; d < 4; ++d) o_acc[d][r] = o_acc[d][r] * alpha;
      Ps[wave][(quad * 4 + r) * 32 + col]      = (f16)p0;
      Ps[wave][(quad * 4 + r) * 32 + 16 + col] = (f16)p1;
    }
    // P (C-layout) -> A-layout via per-wave LDS region (same-wave DS ordering)
    f16x8 ap = *(const f16x8*)(&Ps[wave][0] + col * 32 + quad * 8);
#pragma unroll
    for (int d = 0; d < 4; ++d) {
      f16x8 bv = *(const f16x8*)(Vt + (d * 16 + col) * 32 + quad * 8);
      o_acc[d] = __builtin_amdgcn_mfma_f32_16x16x32_f16(ap, bv, o_acc[d], 0, 0, 0);
    }
    __syncthreads();
  }
#pragma unroll
  for (int d = 0; d < 4; ++d) {
#pragma unroll
    for (int r = 0; r < 4; ++r) {
      int qr = q0 + wave * 16 + quad * 4 + r;
      float v = o_acc[d][r] / l_i[r];
      O[((size_t)b * T + qr) * C + h * 64 + d * 16 + col] = (f16)v;
    }
  }
}

// ---------------- orchestration ----------------
extern "C" void kernel_launch(void* const* d_in, const int* in_sizes, int n_in,
                              void* d_out, int out_size, void* d_ws, size_t ws_size,
                              hipStream_t stream)
{
  const float* x    = (const float*)d_in[0];
  const float* x0   = (const float*)d_in[1];
  const float* lamR = (const float*)d_in[2];
  const float* lamX = (const float*)d_in[3];
  const float* cs   = (const float*)d_in[4];
  const float* sn   = (const float*)d_in[5];
  const float* Wq   = (const float*)d_in[6];
  const float* Wk   = (const float*)d_in[7];
  const float* Wv   = (const float*)d_in[8];
  const float* Wp   = (const float*)d_in[9];
  const float* Wfc  = (const float*)d_in[10];
  const float* Wmp  = (const float*)d_in[11];
  float* out = (float*)d_out;

  const int B = 2, T = 2048, C = 1024, H = 16;
  const int M = B * T;  // 4096
  const size_t MB = 1ull << 20;
  char* ws = (char*)d_ws;
  f16*   Wq_t   = (f16*)(ws + 0 * MB);    // 2 MB each
  f16*   Wk_t   = (f16*)(ws + 2 * MB);
  f16*   Wv_t   = (f16*)(ws + 4 * MB);
  f16*   Wp_t   = (f16*)(ws + 6 * MB);
  f16*   Wfc_t  = (f16*)(ws + 8 * MB);    // 8 MB  (4096 x 1024)
  f16*   Wmp_t  = (f16*)(ws + 16 * MB);   // 8 MB  (1024 x 4096)
  float* scaled  = (float*)(ws + 24 * MB); // 16 MB fp32
  f16*   pre     = (f16*)(ws + 40 * MB);   // 8 MB; reused as attnOut
  f16*   qb      = (f16*)(ws + 48 * MB);   // 8 MB; reused as pre2
  f16*   kbuf    = (f16*)(ws + 56 * MB);   // 8 MB
  f16*   vbuf    = (f16*)(ws + 64 * MB);   // 8 MB
  float* scaled2 = (float*)(ws + 72 * MB); // 16 MB fp32
  f16*   hbuf    = (f16*)(ws + 88 * MB);   // 32 MB (4096 x 4096 f16)
  f16*   attnOut = pre;
  f16*   pre2    = qb;

  dim3 tb(256);
  // weight convert+transpose (K x N fp32 -> N x K f16)
  wconv_kernel<<<dim3(C/32,   C/32),   tb, 0, stream>>>(Wq,  Wq_t,  C,   C);
  wconv_kernel<<<dim3(C/32,   C/32),   tb, 0, stream>>>(Wk,  Wk_t,  C,   C);
  wconv_kernel<<<dim3(C/32,   C/32),   tb, 0, stream>>>(Wv,  Wv_t,  C,   C);
  wconv_kernel<<<dim3(C/32,   C/32),   tb, 0, stream>>>(Wp,  Wp_t,  C,   C);
  wconv_kernel<<<dim3(4*C/32, C/32),   tb, 0, stream>>>(Wfc, Wfc_t, C,   4*C);
  wconv_kernel<<<dim3(C/32,   4*C/32), tb, 0, stream>>>(Wmp, Wmp_t, 4*C, C);

  scale_rms_kernel<<<M, tb, 0, stream>>>(x, x0, lamR, lamX, scaled, pre);

  gemm_kernel<0><<<dim3(C/128, M/128), tb, 0, stream>>>(pre, Wq_t, nullptr, qb,   M, C, C);
  gemm_kernel<0><<<dim3(C/128, M/128), tb, 0, stream>>>(pre, Wk_t, nullptr, kbuf, M, C, C);
  gemm_kernel<0><<<dim3(C/128, M/128), tb, 0, stream>>>(pre, Wv_t, nullptr, vbuf, M, C, C);

  rope_rms_kernel<<<(M * H) / 4, tb, 0, stream>>>(qb,   cs, sn);
  rope_rms_kernel<<<(M * H) / 4, tb, 0, stream>>>(kbuf, cs, sn);

  attn_kernel<<<dim3(B * H, T / 64), tb, 0, stream>>>(qb, kbuf, vbuf, attnOut);

  gemm_kernel<2><<<dim3(C/128, M/128), tb, 0, stream>>>(attnOut, Wp_t, scaled, scaled2, M, C, C);

  rms_kernel<<<M, tb, 0, stream>>>(scaled2, pre2);

  gemm_kernel<1><<<dim3(4*C/128, M/128), tb, 0, stream>>>(pre2, Wfc_t, nullptr, hbuf, M, 4*C, C);

  gemm_kernel<2><<<dim3(C/128, M/128), tb, 0, stream>>>(hbuf, Wmp_t, scaled2, out, M, C, 4*C);
}